// Round 16
// baseline (518.001 us; speedup 1.0000x reference)
//
#include <hip/hip_runtime.h>
#include <cstddef>
#include <cstdint>

#define BATCH 32
#define CCH   512
#define OCH   1024
#define HW    3136
#define WDIM  56
#define NKT   16           // 512 / BK, BK=32

typedef __attribute__((ext_vector_type(8))) short short8v;  // 8 bf16
typedef __attribute__((ext_vector_type(4))) float f32x4;

// RNE round two fp32 to bf16, packed (x0 -> lo16, x1 -> hi16).
static __device__ __forceinline__ unsigned rne2(float x0, float x1) {
    unsigned u0 = __float_as_uint(x0), u1 = __float_as_uint(x1);
    u0 = u0 + 0x7fffu + ((u0 >> 16) & 1u);
    u1 = u1 + 0x7fffu + ((u1 >> 16) & 1u);
    return (u0 >> 16) | (u1 & 0xffff0000u);
}

// 4 slots of 16B per 64-B row; XOR swizzle (R10/R13-proven).
static __device__ __forceinline__ int physlot4(int s, int row) {
    return (s ^ (row & 3) ^ ((row >> 2) & 3)) & 3;
}

#define GLD_LDS16(gsrc, ldst) \
    __builtin_amdgcn_global_load_lds( \
        (const __attribute__((address_space(1))) void*)(gsrc), \
        (__attribute__((address_space(3))) void*)(ldst), 16, 0, 0)

#define MFMA16(a, bb, c) __builtin_amdgcn_mfma_f32_16x16x32_bf16((a), (bb), (c), 0, 0, 0)

// ---------------------------------------------------------------------------
// K0a: pre-convert weights (RNE bf16) into the LDS image (R10-proven).
// ---------------------------------------------------------------------------
__global__ __launch_bounds__(256) void preconv_w(
    const float* __restrict__ wp, unsigned char* __restrict__ wcvt)
{
    const int id = blockIdx.x * 256 + threadIdx.x;   // 16384 = 1024 o x 16 kt
    const int o = id >> 4, kt = id & 15;
    const float* p = wp + (size_t)o * CCH + kt * 32;
    unsigned char* dst = wcvt + (size_t)o * 1024 + kt * 64;
    float4 v[8];
#pragma unroll
    for (int r = 0; r < 8; ++r) v[r] = *(const float4*)(p + 4 * r);
#pragma unroll
    for (int oc = 0; oc < 4; ++oc) {
        uint4 w;
        w.x = rne2(v[2*oc].x,   v[2*oc].y);
        w.y = rne2(v[2*oc].z,   v[2*oc].w);
        w.z = rne2(v[2*oc+1].x, v[2*oc+1].y);
        w.w = rne2(v[2*oc+1].z, v[2*oc+1].w);
        *(uint4*)(dst + physlot4(oc, o) * 16) = w;
    }
}

// ---------------------------------------------------------------------------
// K0b: convert+transpose input to bin[b][kt][n] 64-B chunks, pre-swizzled
// with physlot4(sub, n) (R13-proven byte-exact LDS image).
// ---------------------------------------------------------------------------
__global__ __launch_bounds__(256) void conv_in(
    const float* __restrict__ in, unsigned char* __restrict__ bin)
{
    const int nt = blockIdx.x;      // 0..48 (64-n tiles)
    const int kt = blockIdx.y;      // 0..15
    const int b  = blockIdx.z;
    const int t  = threadIdx.x;
    __shared__ float sm[32 * 65];

    const int n0 = nt * 64;
    const int row = t >> 3;             // 0..31 (k within tile)
    const int c8  = (t & 7) * 8;        // 0..56
    const float* src = in + ((size_t)b * CCH + kt * 32 + row) * HW + n0 + c8;
    float4 v0 = *(const float4*)src;
    float4 v1 = *(const float4*)(src + 4);
    float* sr = sm + row * 65 + c8;
    sr[0] = v0.x; sr[1] = v0.y; sr[2] = v0.z; sr[3] = v0.w;
    sr[4] = v1.x; sr[5] = v1.y; sr[6] = v1.z; sr[7] = v1.w;
    __syncthreads();

    const int n = t >> 2, sub = t & 3;  // n 0..63, k-octet sub
    const int k0 = sub * 8;
    uint4 w;
    w.x = rne2(sm[(k0 + 0) * 65 + n], sm[(k0 + 1) * 65 + n]);
    w.y = rne2(sm[(k0 + 2) * 65 + n], sm[(k0 + 3) * 65 + n]);
    w.z = rne2(sm[(k0 + 4) * 65 + n], sm[(k0 + 5) * 65 + n]);
    w.w = rne2(sm[(k0 + 6) * 65 + n], sm[(k0 + 7) * 65 + n]);
    *(uint4*)(bin + (((size_t)b * 16 + kt) * HW + n0 + n) * 64 +
              physlot4(sub, n) * 16) = w;
}

// ---------------------------------------------------------------------------
// K1: m97-replica GEMM, R15 + TRIPLE-BUFFERED staging (depth-2 pipeline):
// body(kt) stages kt+2, so each DMA has ~2 kt-periods to land and the per-kt
// drain is a counted vmcnt(4) (only the just-issued stage outstanding) —
// R15's vmcnt(0) exposed full L2 latency every kt. LDS 3x16KB = 48KB ->
// 3 blocks/CU. XCD-grouped block decode (R15-proven: FETCH 409->71 MB).
// ---------------------------------------------------------------------------
__global__ __launch_bounds__(256, 3) void gemm_m97(
    const unsigned char* __restrict__ wc,  // wcvt image
    const unsigned char* __restrict__ bin, // input image
    const float* __restrict__ bp,          // [1024]
    float* __restrict__ gate,              // d_out
    float* __restrict__ scan)              // ws scan region
{
    // ---- XCD-grouped decode: same-(bx,b) ot-blocks share an XCD ----
    const int id  = blockIdx.x;        // 0..6399
    const int xcd = id & 7;
    const int m   = id >> 3;
    const int ot  = m & 7;             // o-tile 0..7
    const int j   = xcd + 8 * (m >> 3);   // 0..799
    const int bx  = j % 25;            // n-tile
    const int b   = j / 25;            // batch

    const int t  = threadIdx.x;
    const int lane = t & 63;
    const int wid  = t >> 6;           // 0..3
    const int wm = wid >> 1;           // o-strip of 64
    const int wn = wid & 1;            // n-strip of 64
    const int l15 = lane & 15, lko = lane >> 4;

    __shared__ __align__(16) unsigned char lds[49152];  // 3 bufs x (A8K|B8K)

    const int o0 = ot * 128;
    const int n0 = bx * 128;

    // staging sources (per-lane global, wave-uniform linear LDS dest)
    const unsigned char* aSrc = wc + (size_t)(o0 + (t >> 2)) * 1024 + (t & 3) * 16;
    const unsigned char* bSrc = bin + ((size_t)b * 16 * HW + n0) * 64 + t * 16;

    auto stage = [&](int kt, unsigned char* buf) {
#pragma unroll
        for (int jj = 0; jj < 2; ++jj)
            GLD_LDS16(aSrc + kt * 64 + (size_t)(jj * 64) * 1024,
                      buf + jj * 4096 + wid * 1024);
#pragma unroll
        for (int jj = 0; jj < 2; ++jj)
            GLD_LDS16(bSrc + (size_t)kt * (HW * 64) + jj * 4096,
                      buf + 8192 + jj * 4096 + wid * 1024);
    };

    f32x4 acc[4][4] = {};

    // ---- prologue: stage tiles 0,1 into bufs 0,1 ----
    unsigned char* Ar = lds;             // read buffer (tile kt)
    unsigned char* Aq = lds + 16384;     // tile kt+1 (in flight / landed)
    unsigned char* Az = lds + 32768;     // tile kt+2 (staged this iter)
    stage(0, Ar);
    stage(1, Aq);
    asm volatile("s_waitcnt vmcnt(4)" ::: "memory");   // buf0 landed
    __builtin_amdgcn_s_barrier();
    asm volatile("" ::: "memory");

#pragma unroll 1
    for (int kt = 0; kt < NKT; ++kt) {
        // ---- stage tile kt+2 (has 2 kt-periods to land) ----
        if (kt + 2 < NKT) stage(kt + 2, Az);

        // ---- fragments from Ar ----
        short8v af[4], bf[4];
#pragma unroll
        for (int fi = 0; fi < 4; ++fi) {
            const int r = wm * 64 + fi * 16 + l15;
            af[fi] = *(const short8v*)(Ar + r * 64 + physlot4(lko, r) * 16);
        }
#pragma unroll
        for (int g = 0; g < 4; ++g) {
            const int n = wn * 64 + g * 16 + l15;
            bf[g] = *(const short8v*)(Ar + 8192 + n * 64 + physlot4(lko, n) * 16);
        }

        __builtin_amdgcn_s_setprio(1);
#pragma unroll
        for (int fi = 0; fi < 4; ++fi)
#pragma unroll
            for (int g = 0; g < 4; ++g)
                acc[fi][g] = MFMA16(af[fi], bf[g], acc[fi][g]);
        __builtin_amdgcn_s_setprio(0);

        // ---- counted drain: only this iter's 4 DMA loads outstanding ----
        if (kt + 1 < NKT) {
            if (kt + 2 < NKT) asm volatile("s_waitcnt vmcnt(4)" ::: "memory");
            else              asm volatile("s_waitcnt vmcnt(0)" ::: "memory");
            asm volatile("s_waitcnt lgkmcnt(0)" ::: "memory");
            __builtin_amdgcn_s_barrier();
            asm volatile("" ::: "memory");
        }

        // ---- rotate buffers ----
        unsigned char* tmp = Ar; Ar = Aq; Aq = Az; Az = tmp;
    }

    // ---- epilogue: bias + store (R13-proven) ----
    float* dstb = (ot < 4) ? gate : scan;
    const int c0 = o0 & (CCH - 1);
#pragma unroll
    for (int f = 0; f < 4; ++f) {
        const int rowb = wm * 64 + f * 16 + lko * 4;
#pragma unroll
        for (int rg = 0; rg < 4; ++rg) {
            const float bias = bp[o0 + rowb + rg];
            float* drow = dstb + ((size_t)b * CCH + c0 + rowb + rg) * HW;
#pragma unroll
            for (int g = 0; g < 4; ++g) {
                const int n = n0 + wn * 64 + g * 16 + l15;
                if (n < HW) drow[n] = acc[f][g][rg] + bias;
            }
        }
    }
}

// ---------------------------------------------------------------------------
// Fallback GEMM (R0-proven fp32) if ws lacks room for bin.
// ---------------------------------------------------------------------------
__global__ __launch_bounds__(256) void gemm_proj(
    const float* __restrict__ in, const float* __restrict__ wp,
    const float* __restrict__ bp, float* __restrict__ gate,
    float* __restrict__ scan)
{
    const int bx = blockIdx.x, by = blockIdx.y, b = blockIdx.z;
    const int t = threadIdx.x;
    __shared__ float As[16][128];
    __shared__ float Bs[16][64];
    const float* Ab = wp + (size_t)(by * 128) * CCH;
    const float* Bb = in + (size_t)b * CCH * HW + bx * 64;
    float acc[8][4];
#pragma unroll
    for (int i = 0; i < 8; i++)
#pragma unroll
        for (int j = 0; j < 4; j++) acc[i][j] = 0.f;
    const int a_row = t >> 1, a_c = (t & 1) * 8;
    const int b_row = t >> 4, b_n = (t & 15) * 4;
    const int ty = t >> 4, tx = t & 15;
    for (int k0 = 0; k0 < CCH; k0 += 16) {
        float4 av0 = *(const float4*)(Ab + (size_t)a_row * CCH + k0 + a_c);
        float4 av1 = *(const float4*)(Ab + (size_t)a_row * CCH + k0 + a_c + 4);
        float4 bv  = *(const float4*)(Bb + (size_t)(k0 + b_row) * HW + b_n);
        __syncthreads();
        As[a_c + 0][a_row] = av0.x; As[a_c + 1][a_row] = av0.y;
        As[a_c + 2][a_row] = av0.z; As[a_c + 3][a_row] = av0.w;
        As[a_c + 4][a_row] = av1.x; As[a_c + 5][a_row] = av1.y;
        As[a_c + 6][a_row] = av1.z; As[a_c + 7][a_row] = av1.w;
        *(float4*)&Bs[b_row][b_n] = bv;
        __syncthreads();
#pragma unroll
        for (int kk = 0; kk < 16; kk++) {
            float4 a0 = *(const float4*)&As[kk][ty * 8];
            float4 a1 = *(const float4*)&As[kk][ty * 8 + 4];
            float4 bb = *(const float4*)&Bs[kk][tx * 4];
            float av[8] = {a0.x, a0.y, a0.z, a0.w, a1.x, a1.y, a1.z, a1.w};
            float bw[4] = {bb.x, bb.y, bb.z, bb.w};
#pragma unroll
            for (int i = 0; i < 8; i++)
#pragma unroll
                for (int j = 0; j < 4; j++)
                    acc[i][j] = fmaf(av[i], bw[j], acc[i][j]);
        }
    }
    const int n0 = bx * 64 + tx * 4;
#pragma unroll
    for (int i = 0; i < 8; i++) {
        const int o = by * 128 + ty * 8 + i;
        const float bias = bp[o];
        float4 v;
        v.x = acc[i][0] + bias; v.y = acc[i][1] + bias;
        v.z = acc[i][2] + bias; v.w = acc[i][3] + bias;
        float* dst;
        if (o < CCH) dst = gate + ((size_t)b * CCH + o) * HW + n0;
        else         dst = scan + ((size_t)b * CCH + (o - CCH)) * HW + n0;
        *(float4*)dst = v;
    }
}

// ---------------------------------------------------------------------------
// K2: per-(b,c) 2D discounted scan + fused epilogue (R0-proven).
// ---------------------------------------------------------------------------
__global__ __launch_bounds__(64) void scan_fuse(
    const float* __restrict__ in,
    const float* __restrict__ scanb,
    const float* __restrict__ disc,
    const float* __restrict__ gamma,
    float* gate_out)
{
    const int idx = blockIdx.x;
    const int c = idx & (CCH - 1);
    const size_t base = (size_t)idx * HW;
    const float d = disc[c];
    const float g = gamma[0];
    const int lane = threadIdx.x;

    __shared__ float L[WDIM * 57];

    if (lane < WDIM) {
        const int w = lane;
        float acc = 0.f;
#pragma unroll 4
        for (int h = 0; h < WDIM; h++) {
            acc = fmaf(d, acc, scanb[base + h * WDIM + w]);
            L[h * 57 + w] = acc;
        }
    }
    __syncthreads();
    if (lane < WDIM) {
        const int h = lane;
        float acc = 0.f;
#pragma unroll 4
        for (int w = 0; w < WDIM; w++) {
            acc = fmaf(d, acc, L[h * 57 + w]);
            L[h * 57 + w] = acc;
        }
    }
    __syncthreads();
    if (lane < WDIM) {
        const int w = lane;
#pragma unroll 4
        for (int h = 0; h < WDIM; h++) {
            const size_t off = base + h * WDIM + w;
            const float xc = L[h * 57 + w];
            const float sg = 1.f / (1.f + __expf(-xc));
            const float val = fmaf(g * gate_out[off], sg, in[off]);
            gate_out[off] = val;
        }
    }
}

extern "C" void kernel_launch(void* const* d_in, const int* in_sizes, int n_in,
                              void* d_out, int out_size, void* d_ws, size_t ws_size,
                              hipStream_t stream) {
    const float* in = (const float*)d_in[0];
    const float* wp = (const float*)d_in[1];
    const float* bp = (const float*)d_in[2];
    const float* dc = (const float*)d_in[3];
    const float* gm = (const float*)d_in[4];
    float* out = (float*)d_out;

    const size_t scan_bytes = (size_t)BATCH * CCH * HW * 4;    // 205.5 MB
    const size_t wcvt_bytes = (size_t)OCH * CCH * 2;           // 1 MB
    const size_t bin_bytes  = (size_t)BATCH * 16 * HW * 64;    // 102.8 MB
    const bool pre = ws_size >= scan_bytes + wcvt_bytes + bin_bytes;

    unsigned char* wcvt = (unsigned char*)d_ws;
    unsigned char* bin  = (unsigned char*)d_ws + wcvt_bytes;
    float* scanp = (float*)((unsigned char*)d_ws +
                            (pre ? wcvt_bytes + bin_bytes : 0));

    if (pre) {
        preconv_w<<<64, 256, 0, stream>>>(wp, wcvt);
        conv_in<<<dim3(49, 16, BATCH), 256, 0, stream>>>(in, bin);
        gemm_m97<<<6400, 256, 0, stream>>>(wcvt, bin, bp, out, scanp);
    } else {
        gemm_proj<<<dim3(HW / 64, OCH / 128, BATCH), 256, 0, stream>>>(
            in, wp, bp, out, scanp);
    }

    scan_fuse<<<BATCH * CCH, 64, 0, stream>>>(in, scanp, dc, gm, out);
}

// Round 17
// 461.123 us; speedup vs baseline: 1.1233x; 1.1233x over previous
//
#include <hip/hip_runtime.h>
#include <cstddef>
#include <cstdint>

#define BATCH 32
#define CCH   512
#define OCH   1024
#define HW    3136
#define WDIM  56
#define NKT   16           // 512 / BK, BK=32

typedef __attribute__((ext_vector_type(8))) short short8v;  // 8 bf16
typedef __attribute__((ext_vector_type(4))) float f32x4;

// RNE round two fp32 to bf16, packed (x0 -> lo16, x1 -> hi16).
static __device__ __forceinline__ unsigned rne2(float x0, float x1) {
    unsigned u0 = __float_as_uint(x0), u1 = __float_as_uint(x1);
    u0 = u0 + 0x7fffu + ((u0 >> 16) & 1u);
    u1 = u1 + 0x7fffu + ((u1 >> 16) & 1u);
    return (u0 >> 16) | (u1 & 0xffff0000u);
}
// RNE round one fp32 to bf16 (as u16).
static __device__ __forceinline__ unsigned short rne1(float x) {
    unsigned u = __float_as_uint(x);
    return (unsigned short)((u + 0x7fffu + ((u >> 16) & 1u)) >> 16);
}
static __device__ __forceinline__ float bf2f(unsigned short h) {
    return __uint_as_float((unsigned)h << 16);
}

// 4 slots of 16B per 64-B row; XOR swizzle (R10/R13-proven).
static __device__ __forceinline__ int physlot4(int s, int row) {
    return (s ^ (row & 3) ^ ((row >> 2) & 3)) & 3;
}

#define GLD_LDS16(gsrc, ldst) \
    __builtin_amdgcn_global_load_lds( \
        (const __attribute__((address_space(1))) void*)(gsrc), \
        (__attribute__((address_space(3))) void*)(ldst), 16, 0, 0)

#define MFMA16(a, bb, c) __builtin_amdgcn_mfma_f32_16x16x32_bf16((a), (bb), (c), 0, 0, 0)

// ---------------------------------------------------------------------------
// K0a: pre-convert weights (RNE bf16) into the LDS image (R10-proven).
// ---------------------------------------------------------------------------
__global__ __launch_bounds__(256) void preconv_w(
    const float* __restrict__ wp, unsigned char* __restrict__ wcvt)
{
    const int id = blockIdx.x * 256 + threadIdx.x;   // 16384 = 1024 o x 16 kt
    const int o = id >> 4, kt = id & 15;
    const float* p = wp + (size_t)o * CCH + kt * 32;
    unsigned char* dst = wcvt + (size_t)o * 1024 + kt * 64;
    float4 v[8];
#pragma unroll
    for (int r = 0; r < 8; ++r) v[r] = *(const float4*)(p + 4 * r);
#pragma unroll
    for (int oc = 0; oc < 4; ++oc) {
        uint4 w;
        w.x = rne2(v[2*oc].x,   v[2*oc].y);
        w.y = rne2(v[2*oc].z,   v[2*oc].w);
        w.z = rne2(v[2*oc+1].x, v[2*oc+1].y);
        w.w = rne2(v[2*oc+1].z, v[2*oc+1].w);
        *(uint4*)(dst + physlot4(oc, o) * 16) = w;
    }
}

// ---------------------------------------------------------------------------
// K0b: convert+transpose input to bin[b][kt][n] 64-B chunks, pre-swizzled
// with physlot4(sub, n) (R13-proven byte-exact LDS image).
// ---------------------------------------------------------------------------
__global__ __launch_bounds__(256) void conv_in(
    const float* __restrict__ in, unsigned char* __restrict__ bin)
{
    const int nt = blockIdx.x;      // 0..48 (64-n tiles)
    const int kt = blockIdx.y;      // 0..15
    const int b  = blockIdx.z;
    const int t  = threadIdx.x;
    __shared__ float sm[32 * 65];

    const int n0 = nt * 64;
    const int row = t >> 3;             // 0..31 (k within tile)
    const int c8  = (t & 7) * 8;        // 0..56
    const float* src = in + ((size_t)b * CCH + kt * 32 + row) * HW + n0 + c8;
    float4 v0 = *(const float4*)src;
    float4 v1 = *(const float4*)(src + 4);
    float* sr = sm + row * 65 + c8;
    sr[0] = v0.x; sr[1] = v0.y; sr[2] = v0.z; sr[3] = v0.w;
    sr[4] = v1.x; sr[5] = v1.y; sr[6] = v1.z; sr[7] = v1.w;
    __syncthreads();

    const int n = t >> 2, sub = t & 3;  // n 0..63, k-octet sub
    const int k0 = sub * 8;
    uint4 w;
    w.x = rne2(sm[(k0 + 0) * 65 + n], sm[(k0 + 1) * 65 + n]);
    w.y = rne2(sm[(k0 + 2) * 65 + n], sm[(k0 + 3) * 65 + n]);
    w.z = rne2(sm[(k0 + 4) * 65 + n], sm[(k0 + 5) * 65 + n]);
    w.w = rne2(sm[(k0 + 6) * 65 + n], sm[(k0 + 7) * 65 + n]);
    *(uint4*)(bin + (((size_t)b * 16 + kt) * HW + n0 + n) * 64 +
              physlot4(sub, n) * 16) = w;
}

// ---------------------------------------------------------------------------
// K1: m97-replica GEMM (R15 structure: 32KB dbuf, 4 blk/CU, XCD-grouped
// decode). NEW: scan half (ot>=4) stored as RNE bf16 into scanb (ws) —
// gemm WRITE 401->308 MB, scan_fuse reads bf16. Gate half unchanged (fp32
// into d_out, later overwritten in-place by scan_fuse).
// ---------------------------------------------------------------------------
__global__ __launch_bounds__(256, 4) void gemm_m97(
    const unsigned char* __restrict__ wc,  // wcvt image
    const unsigned char* __restrict__ bin, // input image
    const float* __restrict__ bp,          // [1024]
    float* __restrict__ gate,              // d_out (fp32)
    unsigned short* __restrict__ scanb)    // ws (bf16)
{
    // ---- XCD-grouped decode: same-(bx,b) ot-blocks share an XCD ----
    const int id  = blockIdx.x;        // 0..6399
    const int xcd = id & 7;
    const int m   = id >> 3;
    const int ot  = m & 7;             // o-tile 0..7
    const int j   = xcd + 8 * (m >> 3);   // 0..799
    const int bx  = j % 25;            // n-tile
    const int b   = j / 25;            // batch

    const int t  = threadIdx.x;
    const int lane = t & 63;
    const int wid  = t >> 6;           // 0..3
    const int wm = wid >> 1;           // o-strip of 64
    const int wn = wid & 1;            // n-strip of 64
    const int l15 = lane & 15, lko = lane >> 4;

    __shared__ __align__(16) unsigned char lds[32768];
    unsigned char* const A0 = lds;             // 8 KB (128 rows x 64 B)
    unsigned char* const A1 = lds + 8192;
    unsigned char* const B0 = lds + 16384;
    unsigned char* const B1 = lds + 24576;

    const int o0 = ot * 128;
    const int n0 = bx * 128;

    // staging sources (per-lane global, wave-uniform linear LDS dest)
    const unsigned char* aSrc = wc + (size_t)(o0 + (t >> 2)) * 1024 + (t & 3) * 16;
    const unsigned char* bSrc = bin + ((size_t)b * 16 * HW + n0) * 64 + t * 16;

    auto stage = [&](int kt, unsigned char* Ab, unsigned char* Bb) {
#pragma unroll
        for (int jj = 0; jj < 2; ++jj)
            GLD_LDS16(aSrc + kt * 64 + (size_t)(jj * 64) * 1024,
                      Ab + jj * 4096 + wid * 1024);
#pragma unroll
        for (int jj = 0; jj < 2; ++jj)
            GLD_LDS16(bSrc + (size_t)kt * (HW * 64) + jj * 4096,
                      Bb + jj * 4096 + wid * 1024);
    };

    f32x4 acc[4][4] = {};

    auto body = [&](int kt, unsigned char* Ac, unsigned char* Bc,
                    unsigned char* An, unsigned char* Bn) {
        if (kt + 1 < NKT) stage(kt + 1, An, Bn);

        short8v af[4], bf[4];
#pragma unroll
        for (int fi = 0; fi < 4; ++fi) {
            const int r = wm * 64 + fi * 16 + l15;
            af[fi] = *(const short8v*)(Ac + r * 64 + physlot4(lko, r) * 16);
        }
#pragma unroll
        for (int g = 0; g < 4; ++g) {
            const int n = wn * 64 + g * 16 + l15;
            bf[g] = *(const short8v*)(Bc + n * 64 + physlot4(lko, n) * 16);
        }

        __builtin_amdgcn_s_setprio(1);
#pragma unroll
        for (int fi = 0; fi < 4; ++fi)
#pragma unroll
            for (int g = 0; g < 4; ++g)
                acc[fi][g] = MFMA16(af[fi], bf[g], acc[fi][g]);
        __builtin_amdgcn_s_setprio(0);

        asm volatile("s_waitcnt vmcnt(0) lgkmcnt(0)" ::: "memory");
        __builtin_amdgcn_s_barrier();
        asm volatile("" ::: "memory");
    };

    stage(0, A0, B0);
    asm volatile("s_waitcnt vmcnt(0)" ::: "memory");
    __builtin_amdgcn_s_barrier();
    asm volatile("" ::: "memory");

#pragma unroll 1
    for (int kt2 = 0; kt2 < NKT; kt2 += 2) {
        body(kt2,     A0, B0, A1, B1);
        body(kt2 + 1, A1, B1, A0, B0);
    }

    // ---- epilogue: gate -> fp32 d_out, scan -> bf16 ws ----
    const int c0 = o0 & (CCH - 1);
    if (ot < 4) {
#pragma unroll
        for (int f = 0; f < 4; ++f) {
            const int rowb = wm * 64 + f * 16 + lko * 4;
#pragma unroll
            for (int rg = 0; rg < 4; ++rg) {
                const float bias = bp[o0 + rowb + rg];
                float* drow = gate + ((size_t)b * CCH + c0 + rowb + rg) * HW;
#pragma unroll
                for (int g = 0; g < 4; ++g) {
                    const int n = n0 + wn * 64 + g * 16 + l15;
                    if (n < HW) drow[n] = acc[f][g][rg] + bias;
                }
            }
        }
    } else {
#pragma unroll
        for (int f = 0; f < 4; ++f) {
            const int rowb = wm * 64 + f * 16 + lko * 4;
#pragma unroll
            for (int rg = 0; rg < 4; ++rg) {
                const float bias = bp[o0 + rowb + rg];
                unsigned short* drow =
                    scanb + ((size_t)b * CCH + c0 + rowb + rg) * HW;
#pragma unroll
                for (int g = 0; g < 4; ++g) {
                    const int n = n0 + wn * 64 + g * 16 + l15;
                    if (n < HW) drow[n] = rne1(acc[f][g][rg] + bias);
                }
            }
        }
    }
}

// ---------------------------------------------------------------------------
// Fallback GEMM (R0-proven fp32) if ws lacks room for bin.
// ---------------------------------------------------------------------------
__global__ __launch_bounds__(256) void gemm_proj(
    const float* __restrict__ in, const float* __restrict__ wp,
    const float* __restrict__ bp, float* __restrict__ gate,
    float* __restrict__ scan)
{
    const int bx = blockIdx.x, by = blockIdx.y, b = blockIdx.z;
    const int t = threadIdx.x;
    __shared__ float As[16][128];
    __shared__ float Bs[16][64];
    const float* Ab = wp + (size_t)(by * 128) * CCH;
    const float* Bb = in + (size_t)b * CCH * HW + bx * 64;
    float acc[8][4];
#pragma unroll
    for (int i = 0; i < 8; i++)
#pragma unroll
        for (int j = 0; j < 4; j++) acc[i][j] = 0.f;
    const int a_row = t >> 1, a_c = (t & 1) * 8;
    const int b_row = t >> 4, b_n = (t & 15) * 4;
    const int ty = t >> 4, tx = t & 15;
    for (int k0 = 0; k0 < CCH; k0 += 16) {
        float4 av0 = *(const float4*)(Ab + (size_t)a_row * CCH + k0 + a_c);
        float4 av1 = *(const float4*)(Ab + (size_t)a_row * CCH + k0 + a_c + 4);
        float4 bv  = *(const float4*)(Bb + (size_t)(k0 + b_row) * HW + b_n);
        __syncthreads();
        As[a_c + 0][a_row] = av0.x; As[a_c + 1][a_row] = av0.y;
        As[a_c + 2][a_row] = av0.z; As[a_c + 3][a_row] = av0.w;
        As[a_c + 4][a_row] = av1.x; As[a_c + 5][a_row] = av1.y;
        As[a_c + 6][a_row] = av1.z; As[a_c + 7][a_row] = av1.w;
        *(float4*)&Bs[b_row][b_n] = bv;
        __syncthreads();
#pragma unroll
        for (int kk = 0; kk < 16; kk++) {
            float4 a0 = *(const float4*)&As[kk][ty * 8];
            float4 a1 = *(const float4*)&As[kk][ty * 8 + 4];
            float4 bb = *(const float4*)&Bs[kk][tx * 4];
            float av[8] = {a0.x, a0.y, a0.z, a0.w, a1.x, a1.y, a1.z, a1.w};
            float bw[4] = {bb.x, bb.y, bb.z, bb.w};
#pragma unroll
            for (int i = 0; i < 8; i++)
#pragma unroll
                for (int j = 0; j < 4; j++)
                    acc[i][j] = fmaf(av[i], bw[j], acc[i][j]);
        }
    }
    const int n0 = bx * 64 + tx * 4;
#pragma unroll
    for (int i = 0; i < 8; i++) {
        const int o = by * 128 + ty * 8 + i;
        const float bias = bp[o];
        float4 v;
        v.x = acc[i][0] + bias; v.y = acc[i][1] + bias;
        v.z = acc[i][2] + bias; v.w = acc[i][3] + bias;
        float* dst;
        if (o < CCH) dst = gate + ((size_t)b * CCH + o) * HW + n0;
        else         dst = scan + ((size_t)b * CCH + (o - CCH)) * HW + n0;
        *(float4*)dst = v;
    }
}

// ---------------------------------------------------------------------------
// K2: per-(b,c) 2D discounted scan + fused epilogue. BF16 variant reads
// scanb as bf16 (ws); FP32 variant is the R0-proven fallback.
// ---------------------------------------------------------------------------
template <bool BF>
__global__ __launch_bounds__(64) void scan_fuse(
    const float* __restrict__ in,
    const void* __restrict__ scanb_v,
    const float* __restrict__ disc,
    const float* __restrict__ gamma,
    float* gate_out)
{
    const int idx = blockIdx.x;
    const int c = idx & (CCH - 1);
    const size_t base = (size_t)idx * HW;
    const float d = disc[c];
    const float g = gamma[0];
    const int lane = threadIdx.x;

    __shared__ float L[WDIM * 57];

    if (lane < WDIM) {
        const int w = lane;
        float acc = 0.f;
        if constexpr (BF) {
            const unsigned short* sb = (const unsigned short*)scanb_v + base;
#pragma unroll 4
            for (int h = 0; h < WDIM; h++) {
                acc = fmaf(d, acc, bf2f(sb[h * WDIM + w]));
                L[h * 57 + w] = acc;
            }
        } else {
            const float* sb = (const float*)scanb_v + base;
#pragma unroll 4
            for (int h = 0; h < WDIM; h++) {
                acc = fmaf(d, acc, sb[h * WDIM + w]);
                L[h * 57 + w] = acc;
            }
        }
    }
    __syncthreads();
    if (lane < WDIM) {
        const int h = lane;
        float acc = 0.f;
#pragma unroll 4
        for (int w = 0; w < WDIM; w++) {
            acc = fmaf(d, acc, L[h * 57 + w]);
            L[h * 57 + w] = acc;
        }
    }
    __syncthreads();
    if (lane < WDIM) {
        const int w = lane;
#pragma unroll 4
        for (int h = 0; h < WDIM; h++) {
            const size_t off = base + h * WDIM + w;
            const float xc = L[h * 57 + w];
            const float sg = 1.f / (1.f + __expf(-xc));
            const float val = fmaf(g * gate_out[off], sg, in[off]);
            gate_out[off] = val;
        }
    }
}

extern "C" void kernel_launch(void* const* d_in, const int* in_sizes, int n_in,
                              void* d_out, int out_size, void* d_ws, size_t ws_size,
                              hipStream_t stream) {
    const float* in = (const float*)d_in[0];
    const float* wp = (const float*)d_in[1];
    const float* bp = (const float*)d_in[2];
    const float* dc = (const float*)d_in[3];
    const float* gm = (const float*)d_in[4];
    float* out = (float*)d_out;

    const size_t wcvt_bytes  = (size_t)OCH * CCH * 2;          // 1 MB
    const size_t bin_bytes   = (size_t)BATCH * 16 * HW * 64;   // 102.8 MB
    const size_t scanb_bytes = (size_t)BATCH * CCH * HW * 2;   // 102.8 MB
    const size_t scan_f32    = (size_t)BATCH * CCH * HW * 4;   // 205.5 MB
    const bool pre = ws_size >= wcvt_bytes + bin_bytes + scanb_bytes;

    unsigned char*  wcvt  = (unsigned char*)d_ws;
    unsigned char*  bin   = (unsigned char*)d_ws + wcvt_bytes;
    unsigned short* scanb = (unsigned short*)((unsigned char*)d_ws +
                                              wcvt_bytes + bin_bytes);

    if (pre) {
        preconv_w<<<64, 256, 0, stream>>>(wp, wcvt);
        conv_in<<<dim3(49, 16, BATCH), 256, 0, stream>>>(in, bin);
        gemm_m97<<<6400, 256, 0, stream>>>(wcvt, bin, bp, out, scanb);
        scan_fuse<true><<<BATCH * CCH, 64, 0, stream>>>(in, scanb, dc, gm, out);
    } else if (ws_size >= scan_f32) {
        float* scanp = (float*)d_ws;
        gemm_proj<<<dim3(HW / 64, OCH / 128, BATCH), 256, 0, stream>>>(
            in, wp, bp, out, scanp);
        scan_fuse<false><<<BATCH * CCH, 64, 0, stream>>>(in, scanp, dc, gm, out);
    }
}

// Round 18
// 405.102 us; speedup vs baseline: 1.2787x; 1.1383x over previous
//
#include <hip/hip_runtime.h>
#include <cstddef>
#include <cstdint>

#define BATCH 32
#define CCH   512
#define OCH   1024
#define HW    3136
#define WDIM  56
#define NKT   16           // 512 / BK, BK=32

typedef __attribute__((ext_vector_type(8))) short short8v;  // 8 bf16
typedef __attribute__((ext_vector_type(4))) float f32x4;

// RNE round two fp32 to bf16, packed (x0 -> lo16, x1 -> hi16).
static __device__ __forceinline__ unsigned rne2(float x0, float x1) {
    unsigned u0 = __float_as_uint(x0), u1 = __float_as_uint(x1);
    u0 = u0 + 0x7fffu + ((u0 >> 16) & 1u);
    u1 = u1 + 0x7fffu + ((u1 >> 16) & 1u);
    return (u0 >> 16) | (u1 & 0xffff0000u);
}
// RNE round one fp32 to bf16 (as u16).
static __device__ __forceinline__ unsigned short rne1(float x) {
    unsigned u = __float_as_uint(x);
    return (unsigned short)((u + 0x7fffu + ((u >> 16) & 1u)) >> 16);
}
static __device__ __forceinline__ float bf2f(unsigned short h) {
    return __uint_as_float((unsigned)h << 16);
}

// 4 slots of 16B per 64-B row; XOR swizzle (R10/R13-proven).
static __device__ __forceinline__ int physlot4(int s, int row) {
    return (s ^ (row & 3) ^ ((row >> 2) & 3)) & 3;
}

#define GLD_LDS16(gsrc, ldst) \
    __builtin_amdgcn_global_load_lds( \
        (const __attribute__((address_space(1))) void*)(gsrc), \
        (__attribute__((address_space(3))) void*)(ldst), 16, 0, 0)

#define MFMA16(a, bb, c) __builtin_amdgcn_mfma_f32_16x16x32_bf16((a), (bb), (c), 0, 0, 0)

// ---------------------------------------------------------------------------
// K0a: pre-convert weights (RNE bf16) into the LDS image (R10-proven).
// ---------------------------------------------------------------------------
__global__ __launch_bounds__(256) void preconv_w(
    const float* __restrict__ wp, unsigned char* __restrict__ wcvt)
{
    const int id = blockIdx.x * 256 + threadIdx.x;   // 16384 = 1024 o x 16 kt
    const int o = id >> 4, kt = id & 15;
    const float* p = wp + (size_t)o * CCH + kt * 32;
    unsigned char* dst = wcvt + (size_t)o * 1024 + kt * 64;
    float4 v[8];
#pragma unroll
    for (int r = 0; r < 8; ++r) v[r] = *(const float4*)(p + 4 * r);
#pragma unroll
    for (int oc = 0; oc < 4; ++oc) {
        uint4 w;
        w.x = rne2(v[2*oc].x,   v[2*oc].y);
        w.y = rne2(v[2*oc].z,   v[2*oc].w);
        w.z = rne2(v[2*oc+1].x, v[2*oc+1].y);
        w.w = rne2(v[2*oc+1].z, v[2*oc+1].w);
        *(uint4*)(dst + physlot4(oc, o) * 16) = w;
    }
}

// ---------------------------------------------------------------------------
// K0b: convert+transpose input to bin[b][kt][n] 64-B chunks, pre-swizzled
// with physlot4(sub, n) (R13-proven byte-exact LDS image).
// ---------------------------------------------------------------------------
__global__ __launch_bounds__(256) void conv_in(
    const float* __restrict__ in, unsigned char* __restrict__ bin)
{
    const int nt = blockIdx.x;      // 0..48 (64-n tiles)
    const int kt = blockIdx.y;      // 0..15
    const int b  = blockIdx.z;
    const int t  = threadIdx.x;
    __shared__ float sm[32 * 65];

    const int n0 = nt * 64;
    const int row = t >> 3;             // 0..31 (k within tile)
    const int c8  = (t & 7) * 8;        // 0..56
    const float* src = in + ((size_t)b * CCH + kt * 32 + row) * HW + n0 + c8;
    float4 v0 = *(const float4*)src;
    float4 v1 = *(const float4*)(src + 4);
    float* sr = sm + row * 65 + c8;
    sr[0] = v0.x; sr[1] = v0.y; sr[2] = v0.z; sr[3] = v0.w;
    sr[4] = v1.x; sr[5] = v1.y; sr[6] = v1.z; sr[7] = v1.w;
    __syncthreads();

    const int n = t >> 2, sub = t & 3;  // n 0..63, k-octet sub
    const int k0 = sub * 8;
    uint4 w;
    w.x = rne2(sm[(k0 + 0) * 65 + n], sm[(k0 + 1) * 65 + n]);
    w.y = rne2(sm[(k0 + 2) * 65 + n], sm[(k0 + 3) * 65 + n]);
    w.z = rne2(sm[(k0 + 4) * 65 + n], sm[(k0 + 5) * 65 + n]);
    w.w = rne2(sm[(k0 + 6) * 65 + n], sm[(k0 + 7) * 65 + n]);
    *(uint4*)(bin + (((size_t)b * 16 + kt) * HW + n0 + n) * 64 +
              physlot4(sub, n) * 16) = w;
}

// ---------------------------------------------------------------------------
// K1: m97-replica GEMM (R15/R17-proven structure). GB: gate half also
// stored as bf16 into gateb (ws) -> WRITE 301->206 MB; else fp32 to d_out.
// ---------------------------------------------------------------------------
template <bool GB>
__global__ __launch_bounds__(256, 4) void gemm_m97(
    const unsigned char* __restrict__ wc,  // wcvt image
    const unsigned char* __restrict__ bin, // input image
    const float* __restrict__ bp,          // [1024]
    float* __restrict__ gate,              // d_out (fp32, GB=false)
    unsigned short* __restrict__ gateb,    // ws (bf16, GB=true)
    unsigned short* __restrict__ scanb)    // ws (bf16)
{
    // ---- XCD-grouped decode: same-(bx,b) ot-blocks share an XCD ----
    const int id  = blockIdx.x;        // 0..6399
    const int xcd = id & 7;
    const int m   = id >> 3;
    const int ot  = m & 7;             // o-tile 0..7
    const int j   = xcd + 8 * (m >> 3);   // 0..799
    const int bx  = j % 25;            // n-tile
    const int b   = j / 25;            // batch

    const int t  = threadIdx.x;
    const int lane = t & 63;
    const int wid  = t >> 6;           // 0..3
    const int wm = wid >> 1;           // o-strip of 64
    const int wn = wid & 1;            // n-strip of 64
    const int l15 = lane & 15, lko = lane >> 4;

    __shared__ __align__(16) unsigned char lds[32768];
    unsigned char* const A0 = lds;             // 8 KB (128 rows x 64 B)
    unsigned char* const A1 = lds + 8192;
    unsigned char* const B0 = lds + 16384;
    unsigned char* const B1 = lds + 24576;

    const int o0 = ot * 128;
    const int n0 = bx * 128;

    const unsigned char* aSrc = wc + (size_t)(o0 + (t >> 2)) * 1024 + (t & 3) * 16;
    const unsigned char* bSrc = bin + ((size_t)b * 16 * HW + n0) * 64 + t * 16;

    auto stage = [&](int kt, unsigned char* Ab, unsigned char* Bb) {
#pragma unroll
        for (int jj = 0; jj < 2; ++jj)
            GLD_LDS16(aSrc + kt * 64 + (size_t)(jj * 64) * 1024,
                      Ab + jj * 4096 + wid * 1024);
#pragma unroll
        for (int jj = 0; jj < 2; ++jj)
            GLD_LDS16(bSrc + (size_t)kt * (HW * 64) + jj * 4096,
                      Bb + jj * 4096 + wid * 1024);
    };

    f32x4 acc[4][4] = {};

    auto body = [&](int kt, unsigned char* Ac, unsigned char* Bc,
                    unsigned char* An, unsigned char* Bn) {
        if (kt + 1 < NKT) stage(kt + 1, An, Bn);

        short8v af[4], bf[4];
#pragma unroll
        for (int fi = 0; fi < 4; ++fi) {
            const int r = wm * 64 + fi * 16 + l15;
            af[fi] = *(const short8v*)(Ac + r * 64 + physlot4(lko, r) * 16);
        }
#pragma unroll
        for (int g = 0; g < 4; ++g) {
            const int n = wn * 64 + g * 16 + l15;
            bf[g] = *(const short8v*)(Bc + n * 64 + physlot4(lko, n) * 16);
        }

        __builtin_amdgcn_s_setprio(1);
#pragma unroll
        for (int fi = 0; fi < 4; ++fi)
#pragma unroll
            for (int g = 0; g < 4; ++g)
                acc[fi][g] = MFMA16(af[fi], bf[g], acc[fi][g]);
        __builtin_amdgcn_s_setprio(0);

        asm volatile("s_waitcnt vmcnt(0) lgkmcnt(0)" ::: "memory");
        __builtin_amdgcn_s_barrier();
        asm volatile("" ::: "memory");
    };

    stage(0, A0, B0);
    asm volatile("s_waitcnt vmcnt(0)" ::: "memory");
    __builtin_amdgcn_s_barrier();
    asm volatile("" ::: "memory");

#pragma unroll 1
    for (int kt2 = 0; kt2 < NKT; kt2 += 2) {
        body(kt2,     A0, B0, A1, B1);
        body(kt2 + 1, A1, B1, A0, B0);
    }

    // ---- epilogue ----
    const int c0 = o0 & (CCH - 1);
    if (ot < 4) {
#pragma unroll
        for (int f = 0; f < 4; ++f) {
            const int rowb = wm * 64 + f * 16 + lko * 4;
#pragma unroll
            for (int rg = 0; rg < 4; ++rg) {
                const float bias = bp[o0 + rowb + rg];
                const size_t roff = ((size_t)b * CCH + c0 + rowb + rg) * HW;
#pragma unroll
                for (int g = 0; g < 4; ++g) {
                    const int n = n0 + wn * 64 + g * 16 + l15;
                    if (n < HW) {
                        if constexpr (GB) gateb[roff + n] = rne1(acc[f][g][rg] + bias);
                        else              gate[roff + n]  = acc[f][g][rg] + bias;
                    }
                }
            }
        }
    } else {
#pragma unroll
        for (int f = 0; f < 4; ++f) {
            const int rowb = wm * 64 + f * 16 + lko * 4;
#pragma unroll
            for (int rg = 0; rg < 4; ++rg) {
                const float bias = bp[o0 + rowb + rg];
                unsigned short* drow =
                    scanb + ((size_t)b * CCH + c0 + rowb + rg) * HW;
#pragma unroll
                for (int g = 0; g < 4; ++g) {
                    const int n = n0 + wn * 64 + g * 16 + l15;
                    if (n < HW) drow[n] = rne1(acc[f][g][rg] + bias);
                }
            }
        }
    }
}

// ---------------------------------------------------------------------------
// Fallback GEMM (R0-proven fp32) if ws lacks room for bin.
// ---------------------------------------------------------------------------
__global__ __launch_bounds__(256) void gemm_proj(
    const float* __restrict__ in, const float* __restrict__ wp,
    const float* __restrict__ bp, float* __restrict__ gate,
    float* __restrict__ scan)
{
    const int bx = blockIdx.x, by = blockIdx.y, b = blockIdx.z;
    const int t = threadIdx.x;
    __shared__ float As[16][128];
    __shared__ float Bs[16][64];
    const float* Ab = wp + (size_t)(by * 128) * CCH;
    const float* Bb = in + (size_t)b * CCH * HW + bx * 64;
    float acc[8][4];
#pragma unroll
    for (int i = 0; i < 8; i++)
#pragma unroll
        for (int j = 0; j < 4; j++) acc[i][j] = 0.f;
    const int a_row = t >> 1, a_c = (t & 1) * 8;
    const int b_row = t >> 4, b_n = (t & 15) * 4;
    const int ty = t >> 4, tx = t & 15;
    for (int k0 = 0; k0 < CCH; k0 += 16) {
        float4 av0 = *(const float4*)(Ab + (size_t)a_row * CCH + k0 + a_c);
        float4 av1 = *(const float4*)(Ab + (size_t)a_row * CCH + k0 + a_c + 4);
        float4 bv  = *(const float4*)(Bb + (size_t)(k0 + b_row) * HW + b_n);
        __syncthreads();
        As[a_c + 0][a_row] = av0.x; As[a_c + 1][a_row] = av0.y;
        As[a_c + 2][a_row] = av0.z; As[a_c + 3][a_row] = av0.w;
        As[a_c + 4][a_row] = av1.x; As[a_c + 5][a_row] = av1.y;
        As[a_c + 6][a_row] = av1.z; As[a_c + 7][a_row] = av1.w;
        *(float4*)&Bs[b_row][b_n] = bv;
        __syncthreads();
#pragma unroll
        for (int kk = 0; kk < 16; kk++) {
            float4 a0 = *(const float4*)&As[kk][ty * 8];
            float4 a1 = *(const float4*)&As[kk][ty * 8 + 4];
            float4 bb = *(const float4*)&Bs[kk][tx * 4];
            float av[8] = {a0.x, a0.y, a0.z, a0.w, a1.x, a1.y, a1.z, a1.w};
            float bw[4] = {bb.x, bb.y, bb.z, bb.w};
#pragma unroll
            for (int i = 0; i < 8; i++)
#pragma unroll
                for (int j = 0; j < 4; j++)
                    acc[i][j] = fmaf(av[i], bw[j], acc[i][j]);
        }
    }
    const int n0 = bx * 64 + tx * 4;
#pragma unroll
    for (int i = 0; i < 8; i++) {
        const int o = by * 128 + ty * 8 + i;
        const float bias = bp[o];
        float4 v;
        v.x = acc[i][0] + bias; v.y = acc[i][1] + bias;
        v.z = acc[i][2] + bias; v.w = acc[i][3] + bias;
        float* dst;
        if (o < CCH) dst = gate + ((size_t)b * CCH + o) * HW + n0;
        else         dst = scan + ((size_t)b * CCH + (o - CCH)) * HW + n0;
        *(float4*)dst = v;
    }
}

// ---------------------------------------------------------------------------
// K2: 2D discounted scan + fused epilogue. 4 channels per 256-thr block.
// MODE 2: scanb bf16 + gate bf16 (ws), out = d_out (write-only).
// MODE 1: scanb bf16 (ws), gate fp32 in d_out (read-modify-write in place).
// MODE 0: all fp32 (fallback).
// ---------------------------------------------------------------------------
template <int MODE>
__global__ __launch_bounds__(256) void scan_fuse(
    const float* __restrict__ in,
    const void* __restrict__ scanb_v,
    const void* __restrict__ gate_v,
    const float* __restrict__ disc,
    const float* __restrict__ gamma,
    float* __restrict__ out)
{
    const int idx = blockIdx.x * 4 + (threadIdx.x >> 6);   // b*512 + c
    const int c = idx & (CCH - 1);
    const size_t base = (size_t)idx * HW;
    const float d = disc[c];
    const float g = gamma[0];
    const int lane = threadIdx.x & 63;
    const int ch4  = threadIdx.x >> 6;

    __shared__ float Lm[4][WDIM * 57];
    float* L = Lm[ch4];

    if (lane < WDIM) {
        const int w = lane;
        float acc = 0.f;
        if constexpr (MODE >= 1) {
            const unsigned short* sb = (const unsigned short*)scanb_v + base;
#pragma unroll 4
            for (int h = 0; h < WDIM; h++) {
                acc = fmaf(d, acc, bf2f(sb[h * WDIM + w]));
                L[h * 57 + w] = acc;
            }
        } else {
            const float* sb = (const float*)scanb_v + base;
#pragma unroll 4
            for (int h = 0; h < WDIM; h++) {
                acc = fmaf(d, acc, sb[h * WDIM + w]);
                L[h * 57 + w] = acc;
            }
        }
    }
    __syncthreads();
    if (lane < WDIM) {
        const int h = lane;
        float acc = 0.f;
#pragma unroll 4
        for (int w = 0; w < WDIM; w++) {
            acc = fmaf(d, acc, L[h * 57 + w]);
            L[h * 57 + w] = acc;
        }
    }
    __syncthreads();
    if (lane < WDIM) {
        const int w = lane;
#pragma unroll 4
        for (int h = 0; h < WDIM; h++) {
            const size_t off = base + h * WDIM + w;
            const float xc = L[h * 57 + w];
            const float sg = 1.f / (1.f + __expf(-xc));
            float gv;
            if constexpr (MODE == 2)
                gv = bf2f(((const unsigned short*)gate_v)[off]);
            else
                gv = ((const float*)gate_v)[off];
            out[off] = fmaf(g * gv, sg, in[off]);
        }
    }
}

extern "C" void kernel_launch(void* const* d_in, const int* in_sizes, int n_in,
                              void* d_out, int out_size, void* d_ws, size_t ws_size,
                              hipStream_t stream) {
    const float* in = (const float*)d_in[0];
    const float* wp = (const float*)d_in[1];
    const float* bp = (const float*)d_in[2];
    const float* dc = (const float*)d_in[3];
    const float* gm = (const float*)d_in[4];
    float* out = (float*)d_out;

    const size_t wcvt_bytes  = (size_t)OCH * CCH * 2;          // 1 MB
    const size_t bin_bytes   = (size_t)BATCH * 16 * HW * 64;   // 102.8 MB
    const size_t half_bytes  = (size_t)BATCH * CCH * HW * 2;   // 102.8 MB
    const size_t scan_f32    = (size_t)BATCH * CCH * HW * 4;   // 205.5 MB

    unsigned char*  wcvt  = (unsigned char*)d_ws;
    unsigned char*  bin   = (unsigned char*)d_ws + wcvt_bytes;
    unsigned short* scanb = (unsigned short*)(bin + bin_bytes);
    unsigned short* gateb = (unsigned short*)((unsigned char*)scanb + half_bytes);

    const int nblk = BATCH * CCH / 4;

    if (ws_size >= wcvt_bytes + bin_bytes + 2 * half_bytes) {
        // tier 2: both halves bf16; d_out write-only
        preconv_w<<<64, 256, 0, stream>>>(wp, wcvt);
        conv_in<<<dim3(49, 16, BATCH), 256, 0, stream>>>(in, bin);
        gemm_m97<true><<<6400, 256, 0, stream>>>(wcvt, bin, bp, out, gateb, scanb);
        scan_fuse<2><<<nblk, 256, 0, stream>>>(in, scanb, gateb, dc, gm, out);
    } else if (ws_size >= wcvt_bytes + bin_bytes + half_bytes) {
        // tier 1 (R17-proven): scan half bf16, gate fp32 in d_out
        preconv_w<<<64, 256, 0, stream>>>(wp, wcvt);
        conv_in<<<dim3(49, 16, BATCH), 256, 0, stream>>>(in, bin);
        gemm_m97<false><<<6400, 256, 0, stream>>>(wcvt, bin, bp, out, nullptr, scanb);
        scan_fuse<1><<<nblk, 256, 0, stream>>>(in, scanb, out, dc, gm, out);
    } else if (ws_size >= scan_f32) {
        // tier 0: fp32 fallback
        float* scanp = (float*)d_ws;
        gemm_proj<<<dim3(HW / 64, OCH / 128, BATCH), 256, 0, stream>>>(
            in, wp, bp, out, scanp);
        scan_fuse<0><<<nblk, 256, 0, stream>>>(in, scanp, out, dc, gm, out);
    }
}